// Round 1
// baseline (2383.151 us; speedup 1.0000x reference)
//
#include <hip/hip_runtime.h>

// 3-layer LSTM, B=1024, T=512, H=64, gates=256 (PyTorch order i,f,g,o).
// One block per batch element; 4 waves; lane = (gate_type, hidden_unit).
// Weights register-cached per lane for all 512 steps; state broadcast from LDS.
// ws usage: [1024][512][64] fp32 h-sequence (128 MB), layer1 runs in-place.

static constexpr int T_STEPS = 512;
static constexpr int HID = 64;

__device__ __forceinline__ float sig_f(float x) {
    return 1.0f / (1.0f + __expf(-x));
}
__device__ __forceinline__ float tanh_f(float x) {
    // 1 - 2/(e^{2x}+1): saturates correctly at +/-inf
    float e = __expf(2.0f * x);
    return 1.0f - 2.0f / (e + 1.0f);
}

template <int IN, bool WRITE_SEQ, bool FINAL>
__global__ __launch_bounds__(256) void lstm_layer_kernel(
    const float* __restrict__ xseq,   // [B, T, IN]
    const float* __restrict__ w_ih,   // [256, IN]
    const float* __restrict__ w_hh,   // [256, 64]
    const float* __restrict__ b_ih,   // [256]
    const float* __restrict__ b_hh,   // [256]
    float* __restrict__ out_seq,      // [B, T, 64] if WRITE_SEQ
    const float* __restrict__ w_lin,  // [4, 64] if FINAL
    const float* __restrict__ b_lin,  // [4] if FINAL
    float* __restrict__ dout)         // [B, 4] if FINAL
{
    const int b     = blockIdx.x;
    const int tid   = threadIdx.x;
    const int lane  = tid & 63;
    const int wv    = tid >> 6;       // wave id = hidden-unit quarter (0..3)
    const int jsub  = lane & 15;
    const int gtype = lane >> 4;      // 0:i 1:f 2:g 3:o
    const int j     = wv * 16 + jsub; // hidden unit this lane's gtype-0 partner owns
    const int r     = gtype * 64 + j; // gate row in weight matrices

    __shared__ float h_lds[HID];
    __shared__ float x_lds[2][IN];

    // ---- register-cache this lane's weight rows (reused 512 steps) ----
    float wih[IN];
#pragma unroll
    for (int k = 0; k < IN; ++k) wih[k] = w_ih[r * IN + k];
    float whh[HID];
#pragma unroll
    for (int k = 0; k < HID; ++k) whh[k] = w_hh[r * HID + k];
    const float bias = b_ih[r] + b_hh[r];

    const float* xb = xseq + (long)b * T_STEPS * IN;

    if (wv == 0 && lane < IN) x_lds[0][lane] = xb[lane];
    if (wv == 1) h_lds[lane & (HID - 1)] = 0.0f;
    __syncthreads();

    float c = 0.0f;
    int cur = 0;

    for (int t = 0; t < T_STEPS; ++t) {
        // prefetch x_{t+1} (issued early; consumed after the first barrier)
        float xnext = 0.0f;
        if (wv == 0 && lane < IN) {
            int tn = (t + 1 < T_STEPS) ? (t + 1) : t;
            xnext = xb[(long)tn * IN + lane];
        }

        // ---- gate preactivation: dot(w_row, [x_t | h]) via LDS broadcast ----
        float a0 = 0.f, a1 = 0.f, a2 = 0.f, a3 = 0.f;
        const float4* xv = reinterpret_cast<const float4*>(x_lds[cur]);
#pragma unroll
        for (int k4 = 0; k4 < IN / 4; ++k4) {
            float4 v = xv[k4];
            a0 = fmaf(wih[4 * k4 + 0], v.x, a0);
            a1 = fmaf(wih[4 * k4 + 1], v.y, a1);
            a2 = fmaf(wih[4 * k4 + 2], v.z, a2);
            a3 = fmaf(wih[4 * k4 + 3], v.w, a3);
        }
        const float4* hv = reinterpret_cast<const float4*>(h_lds);
#pragma unroll
        for (int k4 = 0; k4 < HID / 4; ++k4) {
            float4 v = hv[k4];
            a0 = fmaf(whh[4 * k4 + 0], v.x, a0);
            a1 = fmaf(whh[4 * k4 + 1], v.y, a1);
            a2 = fmaf(whh[4 * k4 + 2], v.z, a2);
            a3 = fmaf(whh[4 * k4 + 3], v.w, a3);
        }
        float pre = ((a0 + a1) + (a2 + a3)) + bias;

        // ---- activations + in-wave gate combine ----
        float act = (gtype == 2) ? tanh_f(pre) : sig_f(pre);
        float gf = __shfl(act, jsub + 16, 64);
        float gg = __shfl(act, jsub + 32, 64);
        float go = __shfl(act, jsub + 48, 64);

        float hval = 0.0f;
        if (gtype == 0) {
            c = gf * c + act * gg;   // act == sigmoid(i) on gtype-0 lanes
            hval = go * tanh_f(c);
        }

        __syncthreads();  // everyone done reading h_lds / x_lds[cur]
        if (gtype == 0) {
            h_lds[j] = hval;
            if (WRITE_SEQ) out_seq[((long)b * T_STEPS + t) * HID + j] = hval;
        }
        if (wv == 0 && lane < IN) x_lds[cur ^ 1][lane] = xnext;
        __syncthreads();  // new h / x visible
        cur ^= 1;
    }

    if (FINAL) {
        // h_lds holds h_{T-1}; out[b,o] = h . w_lin[o,:] + b_lin[o]
        if (tid < 4) {
            float acc = b_lin[tid];
#pragma unroll
            for (int k = 0; k < HID; ++k)
                acc = fmaf(h_lds[k], w_lin[tid * HID + k], acc);
            dout[b * 4 + tid] = acc;
        }
    }
}

extern "C" void kernel_launch(void* const* d_in, const int* in_sizes, int n_in,
                              void* d_out, int out_size, void* d_ws, size_t ws_size,
                              hipStream_t stream) {
    const float* x     = (const float*)d_in[0];
    const float* w_ih0 = (const float*)d_in[1];
    const float* w_hh0 = (const float*)d_in[2];
    const float* b_ih0 = (const float*)d_in[3];
    const float* b_hh0 = (const float*)d_in[4];
    const float* w_ih1 = (const float*)d_in[5];
    const float* w_hh1 = (const float*)d_in[6];
    const float* b_ih1 = (const float*)d_in[7];
    const float* b_hh1 = (const float*)d_in[8];
    const float* w_ih2 = (const float*)d_in[9];
    const float* w_hh2 = (const float*)d_in[10];
    const float* b_ih2 = (const float*)d_in[11];
    const float* b_hh2 = (const float*)d_in[12];
    const float* w_lin = (const float*)d_in[13];
    const float* b_lin = (const float*)d_in[14];

    float* hseq = (float*)d_ws;  // [1024][512][64] fp32 = 128 MB

    dim3 grid(1024), block(256);

    // layer 0: x -> hseq
    lstm_layer_kernel<24, true, false><<<grid, block, 0, stream>>>(
        x, w_ih0, w_hh0, b_ih0, b_hh0, hseq, nullptr, nullptr, nullptr);
    // layer 1: hseq -> hseq (in-place is safe: each block owns its batch row,
    // reads [b,t]/[b,t+1] before overwriting [b,t])
    lstm_layer_kernel<64, true, false><<<grid, block, 0, stream>>>(
        hseq, w_ih1, w_hh1, b_ih1, b_hh1, hseq, nullptr, nullptr, nullptr);
    // layer 2: hseq -> final linear -> d_out
    lstm_layer_kernel<64, false, true><<<grid, block, 0, stream>>>(
        hseq, w_ih2, w_hh2, b_ih2, b_hh2, nullptr, w_lin, b_lin, (float*)d_out);
}

// Round 2
// 944.760 us; speedup vs baseline: 2.5225x; 2.5225x over previous
//
#include <hip/hip_runtime.h>

// 3-layer LSTM (B=1024, T=512, H=64) fully fused, f16 MFMA, fp32 cell state.
// grid = 64 blocks x 16 batches; 4 waves/block; wave w owns units [16w,16w+16)
// for ALL 4 gate types (i,f,g,o) -> cell update is lane-local.
// mfma_f32_16x16x32_f16: A row = lane&15 (batch), k-chunk = (lane>>4)*8.
//                        D col = lane&15 (unit),  row = (lane>>4)*4+reg (batch).
// LDS state: chunk-major [K/8][16 batches][8 halves], XOR-swizzled (2-way free).
// h never touches HBM; only x is streamed (prefetched 1 step ahead).

typedef __attribute__((ext_vector_type(8))) _Float16 half8;
typedef __attribute__((ext_vector_type(4))) _Float16 half4;
typedef __attribute__((ext_vector_type(4))) float floatx4;

static constexpr int T_STEPS = 512;

#define NL2E  (-1.4426950408889634f)   // -log2(e)
#define N2L2E (-2.8853900817779268f)   // -2*log2(e)

// LDS geometry in "cr" rows of 256B = [16 batches][8 f16]
#define CR_B0  0     // 192 crs: layer-0 B frags [wave][tile][chunk 0..11]
#define CR_X   192   // 8 crs: x staging, 2 buffers x 4 chunks (k=24..31 zero pad)
#define CR_H0  200   // 8 crs (64 units / 8)
#define CR_H1  208
#define CR_H2  216
#define CR_TOT 224   // 57344 B

__device__ __forceinline__ int lds_off(int cr, int inner) {
    return (cr * 16 + (inner ^ (cr & 7))) * 16;   // byte offset, 16B granules
}

__device__ __forceinline__ floatx4 mfma16(half8 a, half8 b, floatx4 c) {
    return __builtin_amdgcn_mfma_f32_16x16x32_f16(a, b, c, 0, 0, 0);
}

// sigmoid with pre-scaled arg: sig2(a) = 1/(1+2^a); caller passes a = -(x)*log2e
__device__ __forceinline__ float sig2(float a) {
    return __builtin_amdgcn_rcpf(1.0f + __builtin_amdgcn_exp2f(a));
}

__device__ __forceinline__ void act_update(const floatx4* acc, const float* bs,
                                           float* cst, float* hnew) {
#pragma unroll
    for (int r = 0; r < 4; ++r) {
        float ig = sig2(fmaf(acc[0][r], NL2E,  bs[0]));
        float fg = sig2(fmaf(acc[1][r], NL2E,  bs[1]));
        float gg = fmaf(2.0f, sig2(fmaf(acc[2][r], N2L2E, bs[2])), -1.0f);
        float og = sig2(fmaf(acc[3][r], NL2E,  bs[3]));
        float c  = fmaf(fg, cst[r], ig * gg);
        cst[r]   = c;
        float th = fmaf(2.0f, sig2(c * N2L2E), -1.0f);
        hnew[r]  = og * th;
    }
}

__device__ __forceinline__ void write_h(char* sm, int hbase, int u, int l4,
                                        const float* hnew) {
    const int cr = hbase + (u >> 3);
    const int eo = (u & 7) * 2;
#pragma unroll
    for (int r = 0; r < 4; ++r) {
        int bb = l4 * 4 + r;
        *(_Float16*)(&sm[lds_off(cr, bb) + eo]) = (_Float16)hnew[r];
    }
}

__global__ __launch_bounds__(256, 1) void lstm3_mfma(
    const float* __restrict__ x,
    const float* __restrict__ w_ih0, const float* __restrict__ w_hh0,
    const float* __restrict__ b_ih0, const float* __restrict__ b_hh0,
    const float* __restrict__ w_ih1, const float* __restrict__ w_hh1,
    const float* __restrict__ b_ih1, const float* __restrict__ b_hh1,
    const float* __restrict__ w_ih2, const float* __restrict__ w_hh2,
    const float* __restrict__ b_ih2, const float* __restrict__ b_hh2,
    const float* __restrict__ w_lin, const float* __restrict__ b_lin,
    float* __restrict__ out)
{
    __shared__ __align__(16) char sm[CR_TOT * 256];
    const int tid = threadIdx.x;
    const int lane = tid & 63;
    const int w   = tid >> 6;        // wave 0..3 -> units 16w..16w+16
    const int l15 = lane & 15;
    const int l4  = lane >> 4;       // 0..3
    const int b0  = blockIdx.x * 16; // global batch base
    const int u   = w * 16 + l15;    // this lane's hidden unit

    // ---- zero h buffers (24 crs) ----
    for (int i = tid; i < 24 * 16; i += 256)
        *(floatx4*)(&sm[CR_H0 * 256 + i * 16]) = floatx4{0.f, 0.f, 0.f, 0.f};
    // ---- zero x pad chunks (chunk 3 of both buffers: k = 24..31) ----
    if (tid < 32)
        *(floatx4*)(&sm[(CR_X + 3 + (tid >> 4) * 4) * 256 + (tid & 15) * 16]) =
            floatx4{0.f, 0.f, 0.f, 0.f};

    // ---- stage x(t=0) into buffer 0 ----
    if (tid < 96) {
        int xb = tid / 6, xf = tid - xb * 6;          // row, float4 index
        float4 v = *(const float4*)(x + (((long)(b0 + xb) * T_STEPS + 0) * 24 + xf * 4));
        half4 hv; hv[0] = (_Float16)v.x; hv[1] = (_Float16)v.y;
                  hv[2] = (_Float16)v.z; hv[3] = (_Float16)v.w;
        *(half4*)(&sm[lds_off(CR_X + 0 + (xf >> 1), xb) + (xf & 1) * 8]) = hv;
    }

    // ---- fill layer-0 B frags into LDS: [w][t][c][gcol][8], K-axis = x(32)|h0(64) ----
    for (int it = 0; it < 24; ++it) {
        int idx = it * 256 + tid;            // quad index < 6144
        int hh = idx & 1;
        int gcol = (idx >> 1) & 15;
        int rest = idx >> 5;
        int c = rest % 12;
        int rest2 = rest / 12;
        int tt = rest2 & 3;
        int ww = rest2 >> 2;
        int g = tt * 64 + ww * 16 + gcol;
        int k0 = c * 8 + hh * 4;
        half4 hv;
#pragma unroll
        for (int j = 0; j < 4; ++j) {
            int k = k0 + j;
            float v = (k < 24) ? w_ih0[g * 24 + k]
                               : ((k < 32) ? 0.0f : w_hh0[g * 64 + (k - 32)]);
            hv[j] = (_Float16)v;
        }
        int cr = (ww * 4 + tt) * 12 + c;
        *(half4*)(&sm[lds_off(cr, gcol) + hh * 8]) = hv;
    }

    // ---- layer 1/2 B frags, register-resident. K-axis = h_prev(64)|h_own(64) ----
    half8 wf1[4][4], wf2[4][4];
#pragma unroll
    for (int L = 1; L <= 2; ++L) {
        const float* wi = (L == 1) ? w_ih1 : w_ih2;
        const float* wh = (L == 1) ? w_hh1 : w_hh2;
#pragma unroll
        for (int tt = 0; tt < 4; ++tt) {
            int g = tt * 64 + w * 16 + l15;
#pragma unroll
            for (int ks = 0; ks < 4; ++ks) {
                int k0 = ks * 32 + l4 * 8;
                const float* src = (k0 < 64) ? (wi + g * 64 + k0)
                                             : (wh + g * 64 + (k0 - 64));
                float4 v0 = *(const float4*)(src);
                float4 v1 = *(const float4*)(src + 4);
                half8 hv;
                hv[0] = (_Float16)v0.x; hv[1] = (_Float16)v0.y;
                hv[2] = (_Float16)v0.z; hv[3] = (_Float16)v0.w;
                hv[4] = (_Float16)v1.x; hv[5] = (_Float16)v1.y;
                hv[6] = (_Float16)v1.z; hv[7] = (_Float16)v1.w;
                if (L == 1) wf1[tt][ks] = hv; else wf2[tt][ks] = hv;
            }
        }
    }

    // ---- biases, pre-scaled for exp2-form activations ----
    float bs0[4], bs1[4], bs2[4];
#pragma unroll
    for (int tt = 0; tt < 4; ++tt) {
        int g = tt * 64 + w * 16 + l15;
        float sc = (tt == 2) ? N2L2E : NL2E;
        bs0[tt] = sc * (b_ih0[g] + b_hh0[g]);
        bs1[tt] = sc * (b_ih1[g] + b_hh1[g]);
        bs2[tt] = sc * (b_ih2[g] + b_hh2[g]);
    }

    float cst0[4] = {0, 0, 0, 0}, cst1[4] = {0, 0, 0, 0}, cst2[4] = {0, 0, 0, 0};

    __syncthreads();

    for (int t = 0; t < T_STEPS; ++t) {
        const int cur = t & 1;
        // ---- prefetch x(t+1) into registers ----
        float4 xpre;
        int xb = tid / 6, xf = tid - xb * 6;
        const bool do_x = (tid < 96) && (t + 1 < T_STEPS);
        if (do_x)
            xpre = *(const float4*)(x + (((long)(b0 + xb) * T_STEPS + (t + 1)) * 24 + xf * 4));

        floatx4 acc[4];
        float hnew[4];

        // ================= layer 0: K = [x(32) | h0(64)] =================
        {
            half8 a0 = *(const half8*)(&sm[lds_off(CR_X + cur * 4 + l4, l15)]);
            half8 a1 = *(const half8*)(&sm[lds_off(CR_H0 + l4, l15)]);
            half8 a2 = *(const half8*)(&sm[lds_off(CR_H0 + 4 + l4, l15)]);
#pragma unroll
            for (int tt = 0; tt < 4; ++tt) {
#pragma unroll
                for (int r = 0; r < 4; ++r) acc[tt][r] = 0.0f;
                int crb = (w * 4 + tt) * 12;
                half8 f0 = *(const half8*)(&sm[lds_off(crb + 0 + l4, l15)]);
                half8 f1 = *(const half8*)(&sm[lds_off(crb + 4 + l4, l15)]);
                half8 f2 = *(const half8*)(&sm[lds_off(crb + 8 + l4, l15)]);
                acc[tt] = mfma16(a0, f0, acc[tt]);
                acc[tt] = mfma16(a1, f1, acc[tt]);
                acc[tt] = mfma16(a2, f2, acc[tt]);
            }
            act_update(acc, bs0, cst0, hnew);
        }
        __syncthreads();                 // all waves done reading h0(t-1)
        write_h(sm, CR_H0, u, l4, hnew);
        __syncthreads();                 // h0(t) visible

        // ================= layer 1: K = [h0(t) | h1(t-1)] =================
        {
            half8 a0 = *(const half8*)(&sm[lds_off(CR_H0 + l4, l15)]);
            half8 a1 = *(const half8*)(&sm[lds_off(CR_H0 + 4 + l4, l15)]);
            half8 a2 = *(const half8*)(&sm[lds_off(CR_H1 + l4, l15)]);
            half8 a3 = *(const half8*)(&sm[lds_off(CR_H1 + 4 + l4, l15)]);
#pragma unroll
            for (int tt = 0; tt < 4; ++tt) {
#pragma unroll
                for (int r = 0; r < 4; ++r) acc[tt][r] = 0.0f;
                acc[tt] = mfma16(a0, wf1[tt][0], acc[tt]);
                acc[tt] = mfma16(a1, wf1[tt][1], acc[tt]);
                acc[tt] = mfma16(a2, wf1[tt][2], acc[tt]);
                acc[tt] = mfma16(a3, wf1[tt][3], acc[tt]);
            }
            act_update(acc, bs1, cst1, hnew);
        }
        __syncthreads();                 // all waves done reading h1(t-1)
        write_h(sm, CR_H1, u, l4, hnew);
        __syncthreads();                 // h1(t) visible

        // ================= layer 2: K = [h1(t) | h2(t-1)] =================
        {
            half8 a0 = *(const half8*)(&sm[lds_off(CR_H1 + l4, l15)]);
            half8 a1 = *(const half8*)(&sm[lds_off(CR_H1 + 4 + l4, l15)]);
            half8 a2 = *(const half8*)(&sm[lds_off(CR_H2 + l4, l15)]);
            half8 a3 = *(const half8*)(&sm[lds_off(CR_H2 + 4 + l4, l15)]);
#pragma unroll
            for (int tt = 0; tt < 4; ++tt) {
#pragma unroll
                for (int r = 0; r < 4; ++r) acc[tt][r] = 0.0f;
                acc[tt] = mfma16(a0, wf2[tt][0], acc[tt]);
                acc[tt] = mfma16(a1, wf2[tt][1], acc[tt]);
                acc[tt] = mfma16(a2, wf2[tt][2], acc[tt]);
                acc[tt] = mfma16(a3, wf2[tt][3], acc[tt]);
            }
            act_update(acc, bs2, cst2, hnew);
        }
        __syncthreads();                 // all waves done reading h2(t-1)
        write_h(sm, CR_H2, u, l4, hnew);
        if (do_x) {                      // commit x(t+1) to the other buffer
            half4 hv; hv[0] = (_Float16)xpre.x; hv[1] = (_Float16)xpre.y;
                      hv[2] = (_Float16)xpre.z; hv[3] = (_Float16)xpre.w;
            *(half4*)(&sm[lds_off(CR_X + (cur ^ 1) * 4 + (xf >> 1), xb) + (xf & 1) * 8]) = hv;
        }
        __syncthreads();                 // h2(t) + x(t+1) visible
    }

    // ---- final linear: out[b,o] = h2[b,:] . w_lin[o,:] + b_lin[o] ----
    if (tid < 64) {
        int bb = tid >> 2, o = tid & 3;
        float acc = b_lin[o];
#pragma unroll
        for (int k = 0; k < 64; ++k) {
            _Float16 hv = *(const _Float16*)(&sm[lds_off(CR_H2 + (k >> 3), bb) + (k & 7) * 2]);
            acc = fmaf((float)hv, w_lin[o * 64 + k], acc);
        }
        out[(b0 + bb) * 4 + o] = acc;
    }
}

extern "C" void kernel_launch(void* const* d_in, const int* in_sizes, int n_in,
                              void* d_out, int out_size, void* d_ws, size_t ws_size,
                              hipStream_t stream) {
    const float* x     = (const float*)d_in[0];
    const float* w_ih0 = (const float*)d_in[1];
    const float* w_hh0 = (const float*)d_in[2];
    const float* b_ih0 = (const float*)d_in[3];
    const float* b_hh0 = (const float*)d_in[4];
    const float* w_ih1 = (const float*)d_in[5];
    const float* w_hh1 = (const float*)d_in[6];
    const float* b_ih1 = (const float*)d_in[7];
    const float* b_hh1 = (const float*)d_in[8];
    const float* w_ih2 = (const float*)d_in[9];
    const float* w_hh2 = (const float*)d_in[10];
    const float* b_ih2 = (const float*)d_in[11];
    const float* b_hh2 = (const float*)d_in[12];
    const float* w_lin = (const float*)d_in[13];
    const float* b_lin = (const float*)d_in[14];

    lstm3_mfma<<<dim3(64), dim3(256), 0, stream>>>(
        x, w_ih0, w_hh0, b_ih0, b_hh0,
        w_ih1, w_hh1, b_ih1, b_hh1,
        w_ih2, w_hh2, b_ih2, b_hh2,
        w_lin, b_lin, (float*)d_out);
}

// Round 3
// 486.618 us; speedup vs baseline: 4.8974x; 1.9415x over previous
//
#include <hip/hip_runtime.h>

// 3-layer LSTM (B=1024, T=512, H=64), f16 MFMA, fp32 cell state.
// grid = 256 blocks x 4 batches; 768 threads = 12 waves = 3 layer-teams x 4.
// Software pipeline: team L computes layer L at t = s - L (skewed), all h
// state double-buffered in LDS -> 2 barriers per macro-step.
// Phase A: each team MFMAs its layer's gate preacts (weights in registers),
//          valid lanes (l4==0, batches 0-3) write float4{i,f,g,o} to pre[].
// Phase C: ALL 768 threads activate exactly 1 cell (L=wave>>2, b=wave&3,
//          u=lane), update fp32 c in-register, write f16 h to LDS.
// mfma_f32_16x16x32_f16: A row = lane&15 (batch), D col = lane&15 (unit),
//                        D row = (lane>>4)*4+reg (batch) -- verified in R2.

typedef __attribute__((ext_vector_type(8))) _Float16 half8;
typedef __attribute__((ext_vector_type(4))) _Float16 half4;
typedef __attribute__((ext_vector_type(4))) float floatx4;

static constexpr int T_STEPS = 512;

#define NL2E  (-1.4426950408889634f)   // -log2(e)
#define N2L2E (-2.8853900817779268f)   // -2*log2(e)

// LDS: "cr" rows of 256B = [16 slots][16B], slot XOR-swizzled by (cr&7).
// CR_X  : [2 buf][4 chunks]  (x frags, k=0..31, 24 real + 8 zero pad)
// CR_Hl : [2 buf][8 chunks]  (h frags, 64 units)
// rows(=A-frag batch rows) 4..15 stay zero forever (zero-init, never written).
#define CR_X   0
#define CR_H0  8
#define CR_H1  24
#define CR_H2  40
#define CR_TOT 56
#define PRE_OFF  (CR_TOT * 256)            // float pre[3][256 cells][4 gates]
#define SM_BYTES (PRE_OFF + 3 * 256 * 4 * 4)

__device__ __forceinline__ int lds_off(int cr, int inner) {
    return (cr * 16 + (inner ^ (cr & 7))) * 16;
}

__device__ __forceinline__ floatx4 mfma16(half8 a, half8 b, floatx4 c) {
    return __builtin_amdgcn_mfma_f32_16x16x32_f16(a, b, c, 0, 0, 0);
}

// sig2(a) = 1/(1+2^a); caller pre-scales arg by -log2(e) (and bias folded).
__device__ __forceinline__ float sig2(float a) {
    return __builtin_amdgcn_rcpf(1.0f + __builtin_amdgcn_exp2f(a));
}

__device__ __forceinline__ half8 cvt8(const float* src) {
    float4 v0 = *(const float4*)(src);
    float4 v1 = *(const float4*)(src + 4);
    half8 h;
    h[0] = (_Float16)v0.x; h[1] = (_Float16)v0.y;
    h[2] = (_Float16)v0.z; h[3] = (_Float16)v0.w;
    h[4] = (_Float16)v1.x; h[5] = (_Float16)v1.y;
    h[6] = (_Float16)v1.z; h[7] = (_Float16)v1.w;
    return h;
}

__global__ __launch_bounds__(768, 3) void lstm3_pipe(
    const float* __restrict__ x,
    const float* __restrict__ w_ih0, const float* __restrict__ w_hh0,
    const float* __restrict__ b_ih0, const float* __restrict__ b_hh0,
    const float* __restrict__ w_ih1, const float* __restrict__ w_hh1,
    const float* __restrict__ b_ih1, const float* __restrict__ b_hh1,
    const float* __restrict__ w_ih2, const float* __restrict__ w_hh2,
    const float* __restrict__ b_ih2, const float* __restrict__ b_hh2,
    const float* __restrict__ w_lin, const float* __restrict__ b_lin,
    float* __restrict__ out)
{
    __shared__ __align__(16) char sm[SM_BYTES];
    float* pre = (float*)(sm + PRE_OFF);

    const int tid  = threadIdx.x;
    const int lane = tid & 63;
    const int wave = tid >> 6;       // 0..11
    const int L    = wave >> 2;      // team / layer 0..2
    const int w    = wave & 3;       // wave within team (= unit group, = act batch)
    const int l15  = lane & 15;
    const int l4   = lane >> 4;
    const int b0   = blockIdx.x * 4; // global batch base (4 per block)

    // ---- zero x + h frag regions (rows 4..15 must stay zero) ----
    for (int i = tid; i < CR_TOT * 16; i += 768)
        *(floatx4*)(&sm[i * 16]) = floatx4{0.f, 0.f, 0.f, 0.f};

    // ---- per-team parameter pointers ----
    const float* wi = (L == 0) ? w_ih0 : (L == 1 ? w_ih1 : w_ih2);
    const float* wh = (L == 0) ? w_hh0 : (L == 1 ? w_hh1 : w_hh2);
    const float* bi = (L == 0) ? b_ih0 : (L == 1 ? b_ih1 : b_ih2);
    const float* bh = (L == 0) ? b_hh0 : (L == 1 ? b_hh1 : b_hh2);
    const int hbase = (L == 0) ? CR_H0 : (L == 1 ? CR_H1 : CR_H2);
    const int pbase = (L == 0) ? CR_X  : (L == 1 ? CR_H0 : CR_H1);

    // ---- register-resident B frags for THIS team's layer ----
    // B operand: lane&15 = gate col, lane>>4 = k-subchunk. K-axis:
    //  L=0: [x(24)+pad(8) | h0(64)] -> 3 k-groups;  L>=1: [h_prev(64)|h_own(64)] -> 4.
    half8 wf[4][4];
#pragma unroll
    for (int tt = 0; tt < 4; ++tt) {
        const int g = tt * 64 + w * 16 + l15;
        if (L == 0) {
            half8 z; 
#pragma unroll
            for (int j = 0; j < 8; ++j) z[j] = (_Float16)0.f;
            wf[tt][0] = (l4 < 3) ? cvt8(w_ih0 + g * 24 + l4 * 8) : z;
            wf[tt][1] = cvt8(w_hh0 + g * 64 + l4 * 8);
            wf[tt][2] = cvt8(w_hh0 + g * 64 + 32 + l4 * 8);
            wf[tt][3] = z;   // unused
        } else {
            wf[tt][0] = cvt8(wi + g * 64 + l4 * 8);
            wf[tt][1] = cvt8(wi + g * 64 + 32 + l4 * 8);
            wf[tt][2] = cvt8(wh + g * 64 + l4 * 8);
            wf[tt][3] = cvt8(wh + g * 64 + 32 + l4 * 8);
        }
    }

    // ---- act-thread constants: cell (L, b=w, u=lane) ----
    float bs[4];
#pragma unroll
    for (int tt = 0; tt < 4; ++tt) {
        float sc = (tt == 2) ? N2L2E : NL2E;
        bs[tt] = sc * (bi[tt * 64 + lane] + bh[tt * 64 + lane]);
    }
    float cst = 0.0f;

    // ---- stage x(t=0) into x buffer 0 ----
    const int xb = tid / 6, xf = tid % 6;   // batch row, float4 index (tid<24)
    if (tid < 24) {
        float4 v = *(const float4*)(x + ((long)(b0 + xb) * T_STEPS + 0) * 24 + xf * 4);
        half4 hv; hv[0] = (_Float16)v.x; hv[1] = (_Float16)v.y;
                  hv[2] = (_Float16)v.z; hv[3] = (_Float16)v.w;
        *(half4*)(&sm[lds_off(CR_X + (xf >> 1), xb) + (xf & 1) * 8]) = hv;
    }
    __syncthreads();

    for (int s = 0; s < T_STEPS + 2; ++s) {
        const int t = s - L;
        const bool active = (t >= 0) && (t < T_STEPS);
        const int par = t & 1;

        // ---- x(s+1) prefetch issue (lands in LDS at end of phase C) ----
        float4 xpre;
        const bool do_x = (tid < 24) && (s + 1 < T_STEPS);
        if (do_x)
            xpre = *(const float4*)(x + ((long)(b0 + xb) * T_STEPS + (s + 1)) * 24 + xf * 4);

        // =============== phase A: MFMA gate preacts -> pre[] ===============
        if (active) {
            floatx4 acc[4];
            if (L == 0) {
                half8 aX  = *(const half8*)(&sm[lds_off(CR_X + par * 4 + l4, l15)]);
                half8 aP0 = *(const half8*)(&sm[lds_off(CR_H0 + (par ^ 1) * 8 + l4, l15)]);
                half8 aP1 = *(const half8*)(&sm[lds_off(CR_H0 + (par ^ 1) * 8 + 4 + l4, l15)]);
#pragma unroll
                for (int tt = 0; tt < 4; ++tt) {
#pragma unroll
                    for (int r = 0; r < 4; ++r) acc[tt][r] = 0.0f;
                    acc[tt] = mfma16(aX,  wf[tt][0], acc[tt]);
                    acc[tt] = mfma16(aP0, wf[tt][1], acc[tt]);
                    acc[tt] = mfma16(aP1, wf[tt][2], acc[tt]);
                }
            } else {
                half8 aI0 = *(const half8*)(&sm[lds_off(pbase + par * 8 + l4, l15)]);
                half8 aI1 = *(const half8*)(&sm[lds_off(pbase + par * 8 + 4 + l4, l15)]);
                half8 aO0 = *(const half8*)(&sm[lds_off(hbase + (par ^ 1) * 8 + l4, l15)]);
                half8 aO1 = *(const half8*)(&sm[lds_off(hbase + (par ^ 1) * 8 + 4 + l4, l15)]);
#pragma unroll
                for (int tt = 0; tt < 4; ++tt) {
#pragma unroll
                    for (int r = 0; r < 4; ++r) acc[tt][r] = 0.0f;
                    acc[tt] = mfma16(aI0, wf[tt][0], acc[tt]);
                    acc[tt] = mfma16(aI1, wf[tt][1], acc[tt]);
                    acc[tt] = mfma16(aO0, wf[tt][2], acc[tt]);
                    acc[tt] = mfma16(aO1, wf[tt][3], acc[tt]);
                }
            }
            if (l4 == 0) {   // rows 0..3 = real batches
#pragma unroll
                for (int r = 0; r < 4; ++r) {
                    floatx4 pv;
                    pv[0] = acc[0][r]; pv[1] = acc[1][r];
                    pv[2] = acc[2][r]; pv[3] = acc[3][r];
                    *(floatx4*)(&pre[(L * 256 + r * 64 + w * 16 + l15) * 4]) = pv;
                }
            }
        }
        __syncthreads();   // B: pre[] visible

        // ======= phase C: 1 cell per thread: activate, update c, write h ====
        if (active) {
            const floatx4 p = *(const floatx4*)(&pre[(L * 256 + w * 64 + lane) * 4]);
            float ig = sig2(fmaf(p[0], NL2E,  bs[0]));
            float fg = sig2(fmaf(p[1], NL2E,  bs[1]));
            float gg = fmaf(2.0f, sig2(fmaf(p[2], N2L2E, bs[2])), -1.0f);
            float og = sig2(fmaf(p[3], NL2E,  bs[3]));
            cst = fmaf(fg, cst, ig * gg);
            float hv = og * fmaf(2.0f, sig2(cst * N2L2E), -1.0f);
            const int c = lane >> 3;
            *(_Float16*)(&sm[lds_off(hbase + par * 8 + c, w) + (lane & 7) * 2]) =
                (_Float16)hv;
        }
        if (do_x) {
            half4 hv; hv[0] = (_Float16)xpre.x; hv[1] = (_Float16)xpre.y;
                      hv[2] = (_Float16)xpre.z; hv[3] = (_Float16)xpre.w;
            *(half4*)(&sm[lds_off(CR_X + ((s + 1) & 1) * 4 + (xf >> 1), xb) + (xf & 1) * 8]) = hv;
        }
        __syncthreads();   // D: h(t), x(s+1) visible
    }

    // ---- final linear: out[b,o] = h2(511) . w_lin[o,:] + b_lin[o] ----
    if (tid < 16) {
        const int bb = tid >> 2, o = tid & 3;
        const int hb = CR_H2 + ((T_STEPS - 1) & 1) * 8;
        float acc = b_lin[o];
#pragma unroll
        for (int k = 0; k < 64; ++k) {
            _Float16 hv = *(const _Float16*)(&sm[lds_off(hb + (k >> 3), bb) + (k & 7) * 2]);
            acc = fmaf((float)hv, w_lin[o * 64 + k], acc);
        }
        out[(b0 + bb) * 4 + o] = acc;
    }
}

extern "C" void kernel_launch(void* const* d_in, const int* in_sizes, int n_in,
                              void* d_out, int out_size, void* d_ws, size_t ws_size,
                              hipStream_t stream) {
    const float* x     = (const float*)d_in[0];
    const float* w_ih0 = (const float*)d_in[1];
    const float* w_hh0 = (const float*)d_in[2];
    const float* b_ih0 = (const float*)d_in[3];
    const float* b_hh0 = (const float*)d_in[4];
    const float* w_ih1 = (const float*)d_in[5];
    const float* w_hh1 = (const float*)d_in[6];
    const float* b_ih1 = (const float*)d_in[7];
    const float* b_hh1 = (const float*)d_in[8];
    const float* w_ih2 = (const float*)d_in[9];
    const float* w_hh2 = (const float*)d_in[10];
    const float* b_ih2 = (const float*)d_in[11];
    const float* b_hh2 = (const float*)d_in[12];
    const float* w_lin = (const float*)d_in[13];
    const float* b_lin = (const float*)d_in[14];

    lstm3_pipe<<<dim3(256), dim3(768), 0, stream>>>(
        x, w_ih0, w_hh0, b_ih0, b_hh0,
        w_ih1, w_hh1, b_ih1, b_hh1,
        w_ih2, w_hh2, b_ih2, b_hh2,
        w_lin, b_lin, (float*)d_out);
}